// Round 12
// baseline (695.893 us; speedup 1.0000x reference)
//
#include <hip/hip_runtime.h>
#include <math.h>

#define EPSV 1e-8f

constexpr int D   = 1024;
constexpr int E   = 64;
constexpr int TOK = 128;   // tokens per block
constexpr int DC  = 16;    // d-chunk (floats)
constexpr int NS  = DC / 4;  // 4 float4 slots per row-chunk
constexpr int T   = 8;     // tokens per thread
constexpr int EX  = 8;     // experts per thread
// block = 128 threads: ty = tid>>3 (0..15) -> 8 tokens each; tx = tid&7 -> 8 experts each

// ---------- prep: expert inverse norms (verified round 3/4) ----------
__global__ __launch_bounds__(256) void expert_norm_kernel(const float* __restrict__ expw,
                                                          float* __restrict__ einv) {
  const int b = blockIdx.x;
  const int tid = threadIdx.x;
  const float4 v = *reinterpret_cast<const float4*>(expw + (size_t)b * D + tid * 4);
  float ss = v.x * v.x + v.y * v.y + v.z * v.z + v.w * v.w;
#pragma unroll
  for (int m = 32; m >= 1; m >>= 1) ss += __shfl_xor(ss, m);
  __shared__ float red[4];
  if ((tid & 63) == 0) red[tid >> 6] = ss;
  __syncthreads();
  if (tid == 0) {
    float t = (red[0] + red[1]) + (red[2] + red[3]);
    einv[b] = 1.0f / (sqrtf(t) + EPSV);
  }
}

// ---------- split-K partial sims: 8x8 register tile, LDS-instruction-minimized ----------
__global__ __launch_bounds__(128, 4) void partial_kernel(const float* __restrict__ tok,
                                                         const float* __restrict__ expw,
                                                         float* __restrict__ ws_sim,
                                                         float* __restrict__ ws_sq,
                                                         const int n_tok,
                                                         const int nslice) {
  __shared__ float4 s_tok4[TOK * NS];   // 8 KB, slot ^ ((row>>3)&3)
  __shared__ float4 s_exp4[E * NS];     // 4 KB, slot ^ ((row>>3)&3)
  __shared__ float  s_part[TOK][NS];    // 2 KB token sumsq partials

  const int tid = threadIdx.x;
  const int ty = tid >> 3, tx = tid & 7;
  const int srow = tid >> 2, sslot = tid & 3;      // token staging: rows srow+32g, g=0..3
  const int erow = tid >> 1, es0 = (tid & 1) * 2;  // expert staging: row erow, slots es0, es0+1
  const int bid = blockIdx.x;
  const int slice = bid % nslice;
  const int bt = (bid / nslice) * TOK;
  const int KS = D / nslice;
  const int k0 = slice * KS;
  const int NCH = KS / DC;

  float acc[T][EX];
#pragma unroll
  for (int k = 0; k < T; ++k)
#pragma unroll
    for (int j = 0; j < EX; ++j) acc[k][j] = 0.f;
  float sqp[4] = {0.f, 0.f, 0.f, 0.f};

  const float* tp = tok + (size_t)(bt + srow) * D + k0 + sslot * 4;
  const float* ep = expw + (size_t)erow * D + k0 + es0 * 4;

  float4 tg[4], eg[2];
#pragma unroll
  for (int g = 0; g < 4; ++g) tg[g] = *reinterpret_cast<const float4*>(tp + (size_t)32 * g * D);
#pragma unroll
  for (int h = 0; h < 2; ++h) eg[h] = *reinterpret_cast<const float4*>(ep + 4 * h);

#pragma unroll 1
  for (int c = 0; c < NCH; ++c) {
    __syncthreads();  // previous chunk's compute done; LDS free
#pragma unroll
    for (int g = 0; g < 4; ++g) {
      const int row = srow + 32 * g;
      s_tok4[row * NS + (sslot ^ ((row >> 3) & 3))] = tg[g];
      sqp[g] += tg[g].x * tg[g].x + tg[g].y * tg[g].y + tg[g].z * tg[g].z + tg[g].w * tg[g].w;
    }
#pragma unroll
    for (int h = 0; h < 2; ++h) {
      const int sl = es0 + h;
      s_exp4[erow * NS + (sl ^ ((erow >> 3) & 3))] = eg[h];
    }
    __syncthreads();
    if (c + 1 < NCH) {   // prefetch next chunk (hides HBM under compute)
      const int off = (c + 1) * DC;
#pragma unroll
      for (int g = 0; g < 4; ++g)
        tg[g] = *reinterpret_cast<const float4*>(tp + (size_t)32 * g * D + off);
#pragma unroll
      for (int h = 0; h < 2; ++h)
        eg[h] = *reinterpret_cast<const float4*>(ep + 4 * h + off);
    }
    // compute chunk c: per d4, 16 ds_read_b128 feed 64 fma4 (ratio 0.25 vs round-4's 0.375)
#pragma unroll
    for (int d4 = 0; d4 < NS; ++d4) {
      float4 ef[EX];
#pragma unroll
      for (int j = 0; j < EX; ++j)
        ef[j] = s_exp4[(tx * 8 + j) * NS + (d4 ^ (tx & 3))];
#pragma unroll
      for (int k = 0; k < T; ++k) {
        const float4 tv = s_tok4[(ty * 8 + k) * NS + (d4 ^ (ty & 3))];
#pragma unroll
        for (int j = 0; j < EX; ++j) {
          acc[k][j] = fmaf(tv.x, ef[j].x, acc[k][j]);
          acc[k][j] = fmaf(tv.y, ef[j].y, acc[k][j]);
          acc[k][j] = fmaf(tv.z, ef[j].z, acc[k][j]);
          acc[k][j] = fmaf(tv.w, ef[j].w, acc[k][j]);
        }
      }
    }
  }

  // write partial sims: token bt+ty*8+k, experts tx*8 .. tx*8+7 (two float4 stores)
#pragma unroll
  for (int k = 0; k < T; ++k) {
    const float4 v0 = make_float4(acc[k][0], acc[k][1], acc[k][2], acc[k][3]);
    const float4 v1 = make_float4(acc[k][4], acc[k][5], acc[k][6], acc[k][7]);
    const size_t base = ((size_t)slice * n_tok + bt + ty * 8 + k) * E + tx * 8;
    *reinterpret_cast<float4*>(ws_sim + base) = v0;
    *reinterpret_cast<float4*>(ws_sim + base + 4) = v1;
  }

  // partial token sumsq
#pragma unroll
  for (int g = 0; g < 4; ++g) s_part[srow + 32 * g][sslot] = sqp[g];
  __syncthreads();
  if (tid < TOK) {
    float ss = 0.f;
#pragma unroll
    for (int p = 0; p < NS; ++p) ss += s_part[tid][p];
    ws_sq[(size_t)slice * n_tok + bt + tid] = ss;
  }
}

// ---------- reduce + selection (round-4 verbatim, runtime slice count) ----------
__global__ __launch_bounds__(256) void select_kernel(const float* __restrict__ ws_sim,
                                                     const float* __restrict__ ws_sq,
                                                     const float* __restrict__ einv_g,
                                                     const float* __restrict__ cache,
                                                     const int n_tok,
                                                     const int nslice,
                                                     float* __restrict__ out_idx,
                                                     float* __restrict__ out_w) {
  const int tid = threadIdx.x;
  const int lane = tid & 63;
  const int w = tid >> 6;
  const float einv = einv_g[lane];
  const float bonus = 0.1f * cache[lane];
  const int t0 = blockIdx.x * 32 + w * 8;

  float sims[8], sss[8];
#pragma unroll
  for (int i = 0; i < 8; ++i) {
    const int t = t0 + i;
    float s = 0.f, q = 0.f;
    for (int sl = 0; sl < nslice; ++sl) {
      s += ws_sim[((size_t)sl * n_tok + t) * E + lane];
      q += ws_sq[(size_t)sl * n_tok + t];
    }
    sims[i] = s;
    sss[i] = q;
  }

#pragma unroll 1
  for (int i = 0; i < 8; ++i) {
    const int token = t0 + i;
    const float tinv = 1.0f / (sqrtf(sss[i]) + EPSV);

    // top-7 by sim, descending, ties -> lowest expert index
    float v = sims[i];
    int vi = lane;
    float cv[7];
    int ci[7];
#pragma unroll
    for (int r = 0; r < 7; ++r) {
      float rv = v;
      int ri = vi;
#pragma unroll
      for (int m = 32; m >= 1; m >>= 1) {
        const float ov = __shfl_xor(rv, m);
        const int oi = __shfl_xor(ri, m);
        if (ov > rv || (ov == rv && oi < ri)) { rv = ov; ri = oi; }
      }
      cv[r] = rv; ci[r] = ri;
      if (vi == ri) v = -INFINITY;
    }

    // reversed order l <-> rank 6-l ; total = cos + bonus
    float tot[7];
    int gi[7];
#pragma unroll
    for (int l = 0; l < 7; ++l) {
      const int ce = ci[6 - l];
      const float ei = __shfl(einv, ce);
      const float bo = __shfl(bonus, ce);
      tot[l] = cv[6 - l] * tinv * ei + bo;
      gi[l] = ce;
    }

    // top-2 of tot (stable)
    float bv = tot[0]; int bl = 0; int bgi = gi[0];
#pragma unroll
    for (int l = 1; l < 7; ++l)
      if (tot[l] > bv) { bv = tot[l]; bl = l; bgi = gi[l]; }
    float sv = -INFINITY; int sgi = 0;
#pragma unroll
    for (int l = 0; l < 7; ++l) {
      if (l == bl) continue;
      if (tot[l] > sv) { sv = tot[l]; sgi = gi[l]; }
    }

    const float ex1 = expf(sv - bv);
    const float z = 1.0f + ex1;
    if (lane == 0) {
      out_idx[2 * token]     = (float)sgi;
      out_idx[2 * token + 1] = (float)bgi;
      out_w[2 * token]     = ex1 / z;
      out_w[2 * token + 1] = 1.0f / z;
    }
  }
}

extern "C" void kernel_launch(void* const* d_in, const int* in_sizes, int n_in,
                              void* d_out, int out_size, void* d_ws, size_t ws_size,
                              hipStream_t stream) {
  const float* tokp  = (const float*)d_in[0];
  const float* expw  = (const float*)d_in[1];
  const float* cache = (const float*)d_in[2];
  float* out = (float*)d_out;

  const int n_tok = in_sizes[0] / D;       // 32768
  const int n_out_idx = n_tok * 2;

  // ws layout (fixed, independent of nslice): [einv 1KB][ws_sq 8 slices][ws_sim nslice slices]
  char* wsb = (char*)d_ws;
  float* einv = (float*)wsb;
  float* ws_sq = (float*)(wsb + 1024);
  float* ws_sim = ws_sq + (size_t)8 * n_tok;
  const size_t base_need = 1024 + (size_t)8 * n_tok * 4;
  const size_t per_slice = (size_t)n_tok * E * 4;

  int nslice = 8;
  if (ws_size < base_need + 8 * per_slice) nslice = 4;
  if (ws_size < base_need + 4 * per_slice) nslice = 2;

  expert_norm_kernel<<<E, 256, 0, stream>>>(expw, einv);
  partial_kernel<<<(n_tok / TOK) * nslice, 128, 0, stream>>>(tokp, expw, ws_sim, ws_sq,
                                                             n_tok, nslice);
  select_kernel<<<n_tok / 32, 256, 0, stream>>>(ws_sim, ws_sq, einv, cache, n_tok, nslice,
                                                out, out + n_out_idx);
}